// Round 14
// baseline (243.289 us; speedup 1.0000x reference)
//
#include <hip/hip_runtime.h>

typedef unsigned short ushort_t;
typedef unsigned int uint_t;
typedef float f32x4 __attribute__((ext_vector_type(4)));
typedef short bf16x8 __attribute__((ext_vector_type(8)));

#define NB_AGG 2048  // = 256 CU x 8 blocks: exactly one full-occupancy pass
#define BSHIFT 7
#define BROWS 128
#define BCAP 4096    // max edges per 128-row bucket (mean 2048, ~45 sigma margin)
#define NCHUNK 256   // edge chunks for multi-split
#define ZP 72        // padded LDS row stride in bf16
#define NREP 32      // stat replica count (cache-line spread)

__device__ __forceinline__ float bf2f_lo(uint_t u) {
    union { uint_t i; float f; } v; v.i = u << 16; return v.f;
}
__device__ __forceinline__ float bf2f_hi(uint_t u) {
    union { uint_t i; float f; } v; v.i = u & 0xffff0000u; return v.f;
}
__device__ __forceinline__ ushort_t f2bf(float f) {
    union { float f; uint_t i; } v; v.f = f;
    uint_t u = v.i;
    uint_t r = (u + 0x7fffu + ((u >> 16) & 1u)) >> 16;   // RNE
    return (ushort_t)r;
}

// ---------------------------------------------- multi-split: local histogram
__global__ __launch_bounds__(256) void hist2_k(const int* __restrict__ dst,
                                               int* __restrict__ H, int E, int nb) {
    __shared__ int h[1024];
    int b = blockIdx.x, t = threadIdx.x;
    for (int i = t; i < nb; i += 256) h[i] = 0;
    __syncthreads();
    int per = (E + NCHUNK - 1) / NCHUNK;
    int lo = b * per, hi = min(E, lo + per);
    for (int e = lo + t; e < hi; e += 256)
        atomicAdd(&h[dst[e] >> BSHIFT], 1);
    __syncthreads();
    for (int i = t; i < nb; i += 256) H[(size_t)i * NCHUNK + b] = h[i];
}

// --------------------------- generic 3-phase exclusive scan of H (<=256K ints)
__global__ __launch_bounds__(256) void scanA_k(const int* __restrict__ v,
                                               int* __restrict__ segsum, int total) {
    int base = blockIdx.x * 1024 + threadIdx.x;
    int s = 0;
#pragma unroll
    for (int i = 0; i < 4; ++i) {
        int idx = base + i * 256;
        if (idx < total) s += v[idx];
    }
    __shared__ int sh[256];
    sh[threadIdx.x] = s;
    __syncthreads();
    for (int off = 128; off > 0; off >>= 1) {
        if (threadIdx.x < off) sh[threadIdx.x] += sh[threadIdx.x + off];
        __syncthreads();
    }
    if (threadIdx.x == 0) segsum[blockIdx.x] = sh[0];
}

__global__ void scanB_k(int* segsum, int nseg) {
    __shared__ int sh[256];
    int t = threadIdx.x;
    int own = (t < nseg) ? segsum[t] : 0;
    sh[t] = own;
    __syncthreads();
    for (int off = 1; off < 256; off <<= 1) {
        int v = (t >= off) ? sh[t - off] : 0;
        __syncthreads();
        sh[t] += v;
        __syncthreads();
    }
    if (t < nseg) segsum[t] = sh[t] - own;
}

__global__ __launch_bounds__(256) void scanC2_k(int* __restrict__ H,
                                                const int* __restrict__ segsum,
                                                int total) {
    int t = threadIdx.x;
    int base = blockIdx.x * 1024 + t * 4;
    int c0 = 0, c1 = 0, c2 = 0, c3 = 0;
    if (base + 0 < total) c0 = H[base + 0];
    if (base + 1 < total) c1 = H[base + 1];
    if (base + 2 < total) c2 = H[base + 2];
    if (base + 3 < total) c3 = H[base + 3];
    int tsum = c0 + c1 + c2 + c3;
    __shared__ int sh[256];
    sh[t] = tsum;
    __syncthreads();
    for (int off = 1; off < 256; off <<= 1) {
        int v = (t >= off) ? sh[t - off] : 0;
        __syncthreads();
        sh[t] += v;
        __syncthreads();
    }
    int excl = segsum[blockIdx.x] + sh[t] - tsum;
    if (base + 0 < total) H[base + 0] = excl;
    if (base + 1 < total) H[base + 1] = excl + c0;
    if (base + 2 < total) H[base + 2] = excl + c0 + c1;
    if (base + 3 < total) H[base + 3] = excl + c0 + c1 + c2;
}

// ------------------------------ scatter packed recs using LDS-only cursors
__global__ __launch_bounds__(256) void scat2_k(const int* __restrict__ src,
                                               const int* __restrict__ dst,
                                               const int* __restrict__ H,
                                               int* __restrict__ colA, int E, int nb) {
    __shared__ int cur[1024];
    int b = blockIdx.x, t = threadIdx.x;
    for (int i = t; i < nb; i += 256) cur[i] = H[(size_t)i * NCHUNK + b];
    __syncthreads();
    int per = (E + NCHUNK - 1) / NCHUNK;
    int lo = b * per, hi = min(E, lo + per);
    for (int e = lo + t; e < hi; e += 256) {
        int d = dst[e];
        int bk = d >> BSHIFT;
        int pos = atomicAdd(&cur[bk], 1);   // LDS atomic
        colA[pos] = (src[e] << BSHIFT) | (d & (BROWS - 1));
    }
}

// ------------------------------- per-bucket counting sort (in place via LDS)
__global__ __launch_bounds__(256) void build_k(int* __restrict__ colA,
                                               const int* __restrict__ H,
                                               float* __restrict__ dinv,
                                               int* __restrict__ rowp,
                                               int N, int E, int nb) {
    __shared__ int recs[BCAP];
    __shared__ int cnt[BROWS], pfx[BROWS], cur[BROWS];
    int b = blockIdx.x, t = threadIdx.x;
    int base = H[(size_t)b * NCHUNK];
    int next = (b + 1 < nb) ? H[(size_t)(b + 1) * NCHUNK] : E;
    int size = next - base;
    if (size > BCAP) size = BCAP;   // safety clamp (never hit for this graph)
    int row0 = b << BSHIFT;

    if (t < BROWS) { cnt[t] = 0; cur[t] = 0; }
    __syncthreads();

    for (int i = t; i < size; i += 256) {
        int r = colA[base + i];
        recs[i] = r;
        atomicAdd(&cnt[r & (BROWS - 1)], 1);
    }
    __syncthreads();

    if (t < BROWS) pfx[t] = cnt[t];
    __syncthreads();
    for (int off = 1; off < BROWS; off <<= 1) {
        int u = 0;
        if (t < BROWS && t >= off) u = pfx[t - off];
        __syncthreads();
        if (t < BROWS) pfx[t] += u;
        __syncthreads();
    }
    if (t < BROWS) {
        int row = row0 + t;
        if (row < N) {
            int ex = pfx[t] - cnt[t];
            rowp[row] = base + ex;
            dinv[row] = rsqrtf((float)cnt[t] + 1.0f);
            if (row == N - 1) rowp[N] = base + pfx[t];
        }
    }
    __syncthreads();

    for (int i = t; i < size; i += 256) {
        int r = recs[i];
        int l = r & (BROWS - 1);
        int pos = base + (pfx[l] - cnt[l]) + atomicAdd(&cur[l], 1);
        colA[pos] = r >> BSHIFT;
    }
}

// ------------------- degree-sorted row permutation (atomic-free multi-split)
// dsA: per-block histogram over 64 degree bins -> DH[bin][blk] (64x64)
__global__ __launch_bounds__(256) void dsA_k(const int* __restrict__ rowp,
                                             int* __restrict__ DH, int N) {
    __shared__ int h[64];
    int b = blockIdx.x, t = threadIdx.x;
    if (t < 64) h[t] = 0;
    __syncthreads();
    int per = (N + 63) / 64;
    int lo = b * per, hi = min(N, lo + per);
    for (int r = lo + t; r < hi; r += 256) {
        int deg = rowp[r + 1] - rowp[r];
        atomicAdd(&h[min(deg, 63)], 1);
    }
    __syncthreads();
    if (t < 64) DH[t * 64 + b] = h[t];
}

// dscan: exclusive scan of the 4096-entry DH, single block
__global__ void dscan_k(int* __restrict__ DH) {
    __shared__ int sh[256];
    int t = threadIdx.x;
    int c[16];
    int s = 0;
#pragma unroll
    for (int i = 0; i < 16; ++i) { c[i] = DH[t * 16 + i]; s += c[i]; }
    sh[t] = s;
    __syncthreads();
    for (int off = 1; off < 256; off <<= 1) {
        int v = (t >= off) ? sh[t - off] : 0;
        __syncthreads();
        sh[t] += v;
        __syncthreads();
    }
    int run = sh[t] - s;
#pragma unroll
    for (int i = 0; i < 16; ++i) { DH[t * 16 + i] = run; run += c[i]; }
}

// dsB: scatter row ids into perm, degree-sorted (LDS cursors, no global atomics)
__global__ __launch_bounds__(256) void dsB_k(const int* __restrict__ rowp,
                                             const int* __restrict__ DH,
                                             int* __restrict__ perm, int N) {
    __shared__ int cur[64];
    int b = blockIdx.x, t = threadIdx.x;
    if (t < 64) cur[t] = DH[t * 64 + b];
    __syncthreads();
    int per = (N + 63) / 64;
    int lo = b * per, hi = min(N, lo + per);
    for (int r = lo + t; r < hi; r += 256) {
        int deg = rowp[r + 1] - rowp[r];
        int pos = atomicAdd(&cur[min(deg, 63)], 1);   // LDS atomic
        perm[pos] = r;
    }
}

// ---------------------- one-time W preconversion: f32 [k][col] -> bf16 [col][k]
__global__ __launch_bounds__(256) void wconv_k(const float* __restrict__ W1,
                                               const float* __restrict__ W2,
                                               const float* __restrict__ W3,
                                               ushort_t* __restrict__ Wb) {
    int t = blockIdx.x * 256 + threadIdx.x;
    if (t >= 3 * 4096) return;
    int l = t >> 12, i = t & 4095;
    int col = i >> 6, k = i & 63;
    const float* W = (l == 0) ? W1 : ((l == 1) ? W2 : W3);
    Wb[(size_t)l * 4096 + col * 64 + k] = f2bf(W[k * 64 + col]);
}

// ------------------------------------------------- GEMM via MFMA (bf16 in/out)
// R11-proven LDS-staged structure. Block = 64 rows, 4 waves; wave = 16 rows.
// W^T preconverted bf16 (wconv_k) -> straight uint4 copy into LDS.
// MODE==0: fp32 input, no BN. MODE==1: bf16 input + folded BN + ReLU in fp32
// while staging z into LDS. Output y = dinv[row]*(f(z)@W), bf16 row-major.
template <int MODE>
__global__ __launch_bounds__(256) void gemm_k(const float* __restrict__ Zf,
                                              const uint2* __restrict__ Zb,
                                              const ushort_t* __restrict__ Wb,
                                              const float* __restrict__ dinv,
                                              const float* __restrict__ cA,
                                              const float* __restrict__ cC,
                                              ushort_t* __restrict__ XW, int N) {
    __shared__ ushort_t WbT[64 * ZP];
    __shared__ ushort_t Zt[64 * ZP];
    __shared__ ushort_t Ot[4][16 * ZP];
    __shared__ float Al[64], Cl[64], Dl[64];
    int t = threadIdx.x;
    int row0 = blockIdx.x * 64;

    if (t < 64) {
        int r = row0 + t;
        Dl[t] = (r < N) ? dinv[r] : 0.0f;
        if (MODE) { Al[t] = cA[t]; Cl[t] = cC[t]; }
    }
    // stage preconverted W^T: 512 uint4 chunks; thread t copies 2
    {
        const uint4* ws = (const uint4*)Wb;
#pragma unroll
        for (int i = 0; i < 2; ++i) {
            int cid = t * 2 + i;              // 0..511 = col (cid>>3), seg (cid&7)
            int col = cid >> 3, seg = cid & 7;
            *(uint4*)&WbT[col * ZP + seg * 8] = ws[cid];
        }
    }
    __syncthreads();   // Al/Cl ready before staging uses them

    // stage z: row = t>>2, colgroup = t&3 (16 cols each)
    {
        int r = t >> 2, cg = t & 3;
        int grow = row0 + r;
        bool gv = grow < N;
#pragma unroll
        for (int q = 0; q < 4; ++q) {
            float4 v;
            if (MODE) {
                uint2 p2 = {0, 0};
                if (gv) p2 = Zb[(size_t)grow * 16 + cg * 4 + q];
                v.x = bf2f_lo(p2.x); v.y = bf2f_hi(p2.x);
                v.z = bf2f_lo(p2.y); v.w = bf2f_hi(p2.y);
                int k = cg * 16 + q * 4;
                v.x = fmaxf(Al[k + 0] * v.x + Cl[k + 0], 0.0f);
                v.y = fmaxf(Al[k + 1] * v.y + Cl[k + 1], 0.0f);
                v.z = fmaxf(Al[k + 2] * v.z + Cl[k + 2], 0.0f);
                v.w = fmaxf(Al[k + 3] * v.w + Cl[k + 3], 0.0f);
            } else {
                if (gv) v = *(const float4*)(Zf + (size_t)grow * 64 + cg * 16 + q * 4);
                else { v.x = v.y = v.z = v.w = 0.0f; }
            }
            uint2 p;
            p.x = (uint_t)f2bf(v.x) | ((uint_t)f2bf(v.y) << 16);
            p.y = (uint_t)f2bf(v.z) | ((uint_t)f2bf(v.w) << 16);
            *(uint2*)&Zt[r * ZP + cg * 16 + q * 4] = p;
        }
    }
    __syncthreads();

    int wv = t >> 6, lane = t & 63;
    int mrow = lane & 15;    // A row / B col / D col
    int kgrp = lane >> 4;    // k-slice 0..3 (8 k each)

    f32x4 acc0 = {0, 0, 0, 0}, acc1 = {0, 0, 0, 0};
    f32x4 acc2 = {0, 0, 0, 0}, acc3 = {0, 0, 0, 0};
#pragma unroll
    for (int ks = 0; ks < 2; ++ks) {
        bf16x8 a = *(bf16x8*)&Zt[(wv * 16 + mrow) * ZP + ks * 32 + kgrp * 8];
        bf16x8 b0 = *(bf16x8*)&WbT[(0 + mrow) * ZP + ks * 32 + kgrp * 8];
        bf16x8 b1 = *(bf16x8*)&WbT[(16 + mrow) * ZP + ks * 32 + kgrp * 8];
        bf16x8 b2 = *(bf16x8*)&WbT[(32 + mrow) * ZP + ks * 32 + kgrp * 8];
        bf16x8 b3 = *(bf16x8*)&WbT[(48 + mrow) * ZP + ks * 32 + kgrp * 8];
        acc0 = __builtin_amdgcn_mfma_f32_16x16x32_bf16(a, b0, acc0, 0, 0, 0);
        acc1 = __builtin_amdgcn_mfma_f32_16x16x32_bf16(a, b1, acc1, 0, 0, 0);
        acc2 = __builtin_amdgcn_mfma_f32_16x16x32_bf16(a, b2, acc2, 0, 0, 0);
        acc3 = __builtin_amdgcn_mfma_f32_16x16x32_bf16(a, b3, acc3, 0, 0, 0);
    }

    // epilogue: scale by dinv, bf16, stage per-wave tile, coalesced store
#pragma unroll
    for (int r = 0; r < 4; ++r) {
        int orow = kgrp * 4 + r;
        float dn = Dl[wv * 16 + orow];
        Ot[wv][orow * ZP + 0 + mrow]  = f2bf(acc0[r] * dn);
        Ot[wv][orow * ZP + 16 + mrow] = f2bf(acc1[r] * dn);
        Ot[wv][orow * ZP + 32 + mrow] = f2bf(acc2[r] * dn);
        Ot[wv][orow * ZP + 48 + mrow] = f2bf(acc3[r] * dn);
    }
#pragma unroll
    for (int i = 0; i < 2; ++i) {
        int cid = lane * 2 + i;           // 0..127 = 16 rows x 8 chunks (16B)
        int orow = cid >> 3, seg = cid & 7;
        int grow = row0 + wv * 16 + orow;
        if (grow < N)
            *(uint4*)(XW + (size_t)grow * 64 + seg * 8) =
                *(uint4*)&Ot[wv][orow * ZP + seg * 8];
    }
}

// ------------------------------------------------- aggregation + BN partials
// R9 pair structure + degree-sorted pairing: rows perm[2p], perm[2p+1] have
// near-equal degree -> slot over-issue ~1.44x (vs 1.67x adjacent-pairing).
// TWO rows per wave: rs = lane>>5, g = (lane>>4)&1, c = lane&15. 16-slot
// chunks; 8 gather instrs x 4 edges = 32 edges in flight per wave.
// y carries dinv[src]; z stored bf16. Stats -> replicated global atomics.
__global__ __launch_bounds__(256) void agg_k(const ushort_t* __restrict__ y,
                                             const int* __restrict__ row_ptr,
                                             const int* __restrict__ colA,
                                             const int* __restrict__ perm,
                                             const float* __restrict__ dinv,
                                             uint2* __restrict__ OUTB,
                                             float* __restrict__ gstat, int N) {
    __shared__ float ssum[64], ssq[64];
    int t = threadIdx.x, lane = t & 63, wv = t >> 6;
    int rs = lane >> 5;          // row within pair
    int g = (lane >> 4) & 1;     // edge group
    int c = lane & 15;           // column quad (cols 4c..4c+3)
    if (t < 64) ssum[t] = 0.0f;
    else if (t < 128) ssq[t - 64] = 0.0f;
    __syncthreads();

    const uint2* y2 = (const uint2*)y;
    float ps0 = 0, ps1 = 0, ps2 = 0, ps3 = 0;
    float pq0 = 0, pq1 = 0, pq2 = 0, pq3 = 0;

    int npair = (N + 1) >> 1;
    for (int p = blockIdx.x * 4 + wv; p < npair; p += NB_AGG * 4) {
        int idx = p * 2 + rs;
        bool rv = idx < N;
        int ic = rv ? idx : N - 1;
        int row = perm[ic];
        int start = row_ptr[row];
        int end = row_ptr[row + 1];
        int len = rv ? (end - start) : 0;
        int ml = max(len, __shfl_xor(len, 32));   // max over the pair

        float a0 = 0, a1 = 0, a2 = 0, a3 = 0;
        for (int off = 0; off < ml; off += 16) {
            int sA[8];
            uint_t mA[8];
#pragma unroll
            for (int u = 0; u < 8; ++u) {
                int slot = off + u * 2 + g;
                bool val = slot < len;
                int ec = val ? (start + slot) : 0;
                sA[u] = colA[ec];
                mA[u] = val ? 0xffffffffu : 0u;
            }
#pragma unroll
            for (int u = 0; u < 8; ++u) {
                uint2 v = y2[(size_t)sA[u] * 16 + c];
                v.x &= mA[u]; v.y &= mA[u];
                a0 += bf2f_lo(v.x);
                a1 += bf2f_hi(v.x);
                a2 += bf2f_lo(v.y);
                a3 += bf2f_hi(v.y);
            }
        }

        // reduce across the 2 edge groups (lane bit 4)
        a0 += __shfl_xor(a0, 16);
        a1 += __shfl_xor(a1, 16);
        a2 += __shfl_xor(a2, 16);
        a3 += __shfl_xor(a3, 16);

        if (g == 0 && rv) {
            float dn = dinv[row];
            uint2 sv = y2[(size_t)row * 16 + c];   // self term (y carries dinv)
            float v0 = dn * (a0 + bf2f_lo(sv.x));
            float v1 = dn * (a1 + bf2f_hi(sv.x));
            float v2 = dn * (a2 + bf2f_lo(sv.y));
            float v3 = dn * (a3 + bf2f_hi(sv.y));
            uint2 pk;
            pk.x = (uint_t)f2bf(v0) | ((uint_t)f2bf(v1) << 16);
            pk.y = (uint_t)f2bf(v2) | ((uint_t)f2bf(v3) << 16);
            OUTB[(size_t)row * 16 + c] = pk;
            ps0 += v0; ps1 += v1; ps2 += v2; ps3 += v3;
            pq0 += v0 * v0; pq1 += v1 * v1; pq2 += v2 * v2; pq3 += v3 * v3;
        }
    }

    if (g == 0) {
        atomicAdd(&ssum[c * 4 + 0], ps0); atomicAdd(&ssq[c * 4 + 0], pq0);
        atomicAdd(&ssum[c * 4 + 1], ps1); atomicAdd(&ssq[c * 4 + 1], pq1);
        atomicAdd(&ssum[c * 4 + 2], ps2); atomicAdd(&ssq[c * 4 + 2], pq2);
        atomicAdd(&ssum[c * 4 + 3], ps3); atomicAdd(&ssq[c * 4 + 3], pq3);
    }
    __syncthreads();
    // replicated global stats: 64 blocks per replica, 8 lines each -> no hot line
    float* gr = gstat + (size_t)(blockIdx.x & (NREP - 1)) * 128;
    if (t < 64) atomicAdd(&gr[t], ssum[t]);
    else if (t < 128) atomicAdd(&gr[t], ssq[t - 64]);
}

// ------------------------- BN coefficients from replicated sums (1 block)
// Reads gstat, computes cA/cC, then re-zeros gstat for the next layer.
__global__ void stats2_k(float* __restrict__ gstat,
                         const float* __restrict__ g,
                         const float* __restrict__ be,
                         float* __restrict__ cA,
                         float* __restrict__ cC, int N) {
    int t = threadIdx.x;
    if (t < 64) {
        float s = 0.0f, q = 0.0f;
        for (int r = 0; r < NREP; ++r) {
            s += gstat[r * 128 + t];
            q += gstat[r * 128 + 64 + t];
        }
        float mu = s / (float)N;
        float var = fmaxf(q / (float)N - mu * mu, 0.0f);
        float a = g[t] * rsqrtf(var + 1e-5f);
        cA[t] = a;
        cC[t] = be[t] - mu * a;
    }
    __syncthreads();
    for (int i = t; i < NREP * 128; i += 256) gstat[i] = 0.0f;
}

// --------------------------------- final BN apply: bf16 z -> fp32 output
__global__ __launch_bounds__(256) void apply_k(const uint2* __restrict__ Zb,
                                               float* __restrict__ O,
                                               const float* __restrict__ cA,
                                               const float* __restrict__ cC,
                                               int N) {
    int total = N * 16;  // uint2 count
    for (int i = blockIdx.x * 256 + threadIdx.x; i < total; i += gridDim.x * 256) {
        uint2 p = Zb[i];
        int c = (i & 15) * 4;
        float4 v;
        v.x = cA[c + 0] * bf2f_lo(p.x) + cC[c + 0];
        v.y = cA[c + 1] * bf2f_hi(p.x) + cC[c + 1];
        v.z = cA[c + 2] * bf2f_lo(p.y) + cC[c + 2];
        v.w = cA[c + 3] * bf2f_hi(p.y) + cC[c + 3];
        ((float4*)O)[i] = v;
    }
}

// ---------------------------------------------------------------------------
extern "C" void kernel_launch(void* const* d_in, const int* in_sizes, int n_in,
                              void* d_out, int out_size, void* d_ws, size_t ws_size,
                              hipStream_t stream) {
    const float* x   = (const float*)d_in[0];
    const int*   ei  = (const int*)d_in[1];
    const float* W1  = (const float*)d_in[2];
    const float* g1  = (const float*)d_in[4];
    const float* be1 = (const float*)d_in[5];
    const float* W2  = (const float*)d_in[6];
    const float* g2  = (const float*)d_in[8];
    const float* be2 = (const float*)d_in[9];
    const float* W3  = (const float*)d_in[10];
    const float* g3  = (const float*)d_in[12];
    const float* be3 = (const float*)d_in[13];

    int N = in_sizes[0] / 64;
    int E = in_sizes[1] / 2;
    const int* srcA = ei;
    const int* dstA = ei + E;
    int nb = (N + BROWS - 1) >> BSHIFT;          // <=1024 for N<=131072
    int total = nb * NCHUNK;                     // multi-split matrix size
    int nseg = (total + 1023) / 1024;            // <=256

    char* w = (char*)d_ws;
    auto alloc = [&](size_t bytes) -> char* {
        char* p = w;
        w += (bytes + 255) & ~(size_t)255;
        return p;
    };
    ushort_t* xw    = (ushort_t*)alloc((size_t)N * 64 * 2);   // staged y (bf16)
    uint2*    zb    = (uint2*)alloc((size_t)N * 64 * 2);      // intermediate z (bf16)
    ushort_t* Wb    = (ushort_t*)alloc((size_t)3 * 4096 * 2); // preconverted W^T
    int*      rowp  = (int*)alloc(((size_t)N + 1) * 4);
    float*    dinv  = (float*)alloc((size_t)N * 4);
    int*      colA  = (int*)alloc((size_t)E * 4);
    int*      perm  = (int*)alloc((size_t)N * 4);             // degree-sorted rows
    int*      H     = (int*)alloc((size_t)total * 4);
    int*      DH    = (int*)alloc((size_t)4096 * 4);
    int*      segsum= (int*)alloc((size_t)nseg * 4);
    float*    gstat = (float*)alloc((size_t)NREP * 128 * 4);  // stat replicas
    float*    cA1 = (float*)alloc(256); float* cC1 = (float*)alloc(256);
    float*    cA2 = (float*)alloc(256); float* cC2 = (float*)alloc(256);
    float*    cA3 = (float*)alloc(256); float* cC3 = (float*)alloc(256);
    (void)ws_size; (void)n_in; (void)out_size;

    float* out = (float*)d_out;

    // ---- CSR build via atomic-free multi-split (once; shared by 3 layers) ----
    hipMemsetAsync(gstat, 0, (size_t)NREP * 128 * 4, stream);
    hist2_k<<<NCHUNK, 256, 0, stream>>>(dstA, H, E, nb);
    scanA_k<<<nseg, 256, 0, stream>>>(H, segsum, total);
    scanB_k<<<1, 256, 0, stream>>>(segsum, nseg);
    scanC2_k<<<nseg, 256, 0, stream>>>(H, segsum, total);
    scat2_k<<<NCHUNK, 256, 0, stream>>>(srcA, dstA, H, colA, E, nb);
    build_k<<<nb, 256, 0, stream>>>(colA, H, dinv, rowp, N, E, nb);
    // degree-sorted row permutation (for balanced pairing in agg)
    dsA_k<<<64, 256, 0, stream>>>(rowp, DH, N);
    dscan_k<<<1, 256, 0, stream>>>(DH);
    dsB_k<<<64, 256, 0, stream>>>(rowp, DH, perm, N);
    wconv_k<<<48, 256, 0, stream>>>(W1, W2, W3, Wb);

    int gemmGrid = (N + 63) / 64;

    // ---- layer 1 ----
    gemm_k<0><<<gemmGrid, 256, 0, stream>>>(x, nullptr, Wb, dinv, nullptr, nullptr, xw, N);
    agg_k<<<NB_AGG, 256, 0, stream>>>(xw, rowp, colA, perm, dinv, zb, gstat, N);
    stats2_k<<<1, 256, 0, stream>>>(gstat, g1, be1, cA1, cC1, N);

    // ---- layer 2 ----
    gemm_k<1><<<gemmGrid, 256, 0, stream>>>(nullptr, zb, Wb + 4096, dinv, cA1, cC1, xw, N);
    agg_k<<<NB_AGG, 256, 0, stream>>>(xw, rowp, colA, perm, dinv, zb, gstat, N);
    stats2_k<<<1, 256, 0, stream>>>(gstat, g2, be2, cA2, cC2, N);

    // ---- layer 3 ----
    gemm_k<1><<<gemmGrid, 256, 0, stream>>>(nullptr, zb, Wb + 8192, dinv, cA2, cC2, xw, N);
    agg_k<<<NB_AGG, 256, 0, stream>>>(xw, rowp, colA, perm, dinv, zb, gstat, N);
    stats2_k<<<1, 256, 0, stream>>>(gstat, g3, be3, cA3, cC3, N);

    // ---- final BN (no relu): bf16 z -> fp32 d_out ----
    apply_k<<<2048, 256, 0, stream>>>(zb, out, cA3, cC3, N);
}

// Round 15
// 229.074 us; speedup vs baseline: 1.0621x; 1.0621x over previous
//
#include <hip/hip_runtime.h>

typedef unsigned short ushort_t;
typedef unsigned int uint_t;
typedef float f32x4 __attribute__((ext_vector_type(4)));
typedef short bf16x8 __attribute__((ext_vector_type(8)));

#define NB_AGG 2048  // = 256 CU x 8 blocks: exactly one full-occupancy pass
#define BSHIFT 7
#define BROWS 128
#define BCAP 4096    // max edges per 128-row bucket (mean 2048, ~45 sigma margin)
#define NCHUNK 256   // edge chunks for multi-split
#define ZP 72        // padded LDS row stride in bf16
#define NREP 32      // stat replica count (cache-line spread)

__device__ __forceinline__ float bf2f_lo(uint_t u) {
    union { uint_t i; float f; } v; v.i = u << 16; return v.f;
}
__device__ __forceinline__ float bf2f_hi(uint_t u) {
    union { uint_t i; float f; } v; v.i = u & 0xffff0000u; return v.f;
}
__device__ __forceinline__ ushort_t f2bf(float f) {
    union { float f; uint_t i; } v; v.f = f;
    uint_t u = v.i;
    uint_t r = (u + 0x7fffu + ((u >> 16) & 1u)) >> 16;   // RNE
    return (ushort_t)r;
}

// ---------------------------------------------- multi-split: local histogram
__global__ __launch_bounds__(256) void hist2_k(const int* __restrict__ dst,
                                               int* __restrict__ H, int E, int nb) {
    __shared__ int h[1024];
    int b = blockIdx.x, t = threadIdx.x;
    for (int i = t; i < nb; i += 256) h[i] = 0;
    __syncthreads();
    int per = (E + NCHUNK - 1) / NCHUNK;
    int lo = b * per, hi = min(E, lo + per);
    for (int e = lo + t; e < hi; e += 256)
        atomicAdd(&h[dst[e] >> BSHIFT], 1);
    __syncthreads();
    for (int i = t; i < nb; i += 256) H[(size_t)i * NCHUNK + b] = h[i];
}

// --------------------------- generic 3-phase exclusive scan of H (<=256K ints)
__global__ __launch_bounds__(256) void scanA_k(const int* __restrict__ v,
                                               int* __restrict__ segsum, int total) {
    int base = blockIdx.x * 1024 + threadIdx.x;
    int s = 0;
#pragma unroll
    for (int i = 0; i < 4; ++i) {
        int idx = base + i * 256;
        if (idx < total) s += v[idx];
    }
    __shared__ int sh[256];
    sh[threadIdx.x] = s;
    __syncthreads();
    for (int off = 128; off > 0; off >>= 1) {
        if (threadIdx.x < off) sh[threadIdx.x] += sh[threadIdx.x + off];
        __syncthreads();
    }
    if (threadIdx.x == 0) segsum[blockIdx.x] = sh[0];
}

__global__ void scanB_k(int* segsum, int nseg) {
    __shared__ int sh[256];
    int t = threadIdx.x;
    int own = (t < nseg) ? segsum[t] : 0;
    sh[t] = own;
    __syncthreads();
    for (int off = 1; off < 256; off <<= 1) {
        int v = (t >= off) ? sh[t - off] : 0;
        __syncthreads();
        sh[t] += v;
        __syncthreads();
    }
    if (t < nseg) segsum[t] = sh[t] - own;
}

__global__ __launch_bounds__(256) void scanC2_k(int* __restrict__ H,
                                                const int* __restrict__ segsum,
                                                int total) {
    int t = threadIdx.x;
    int base = blockIdx.x * 1024 + t * 4;
    int c0 = 0, c1 = 0, c2 = 0, c3 = 0;
    if (base + 0 < total) c0 = H[base + 0];
    if (base + 1 < total) c1 = H[base + 1];
    if (base + 2 < total) c2 = H[base + 2];
    if (base + 3 < total) c3 = H[base + 3];
    int tsum = c0 + c1 + c2 + c3;
    __shared__ int sh[256];
    sh[t] = tsum;
    __syncthreads();
    for (int off = 1; off < 256; off <<= 1) {
        int v = (t >= off) ? sh[t - off] : 0;
        __syncthreads();
        sh[t] += v;
        __syncthreads();
    }
    int excl = segsum[blockIdx.x] + sh[t] - tsum;
    if (base + 0 < total) H[base + 0] = excl;
    if (base + 1 < total) H[base + 1] = excl + c0;
    if (base + 2 < total) H[base + 2] = excl + c0 + c1;
    if (base + 3 < total) H[base + 3] = excl + c0 + c1 + c2;
}

// ------------------------------ scatter packed recs using LDS-only cursors
__global__ __launch_bounds__(256) void scat2_k(const int* __restrict__ src,
                                               const int* __restrict__ dst,
                                               const int* __restrict__ H,
                                               int* __restrict__ colA, int E, int nb) {
    __shared__ int cur[1024];
    int b = blockIdx.x, t = threadIdx.x;
    for (int i = t; i < nb; i += 256) cur[i] = H[(size_t)i * NCHUNK + b];
    __syncthreads();
    int per = (E + NCHUNK - 1) / NCHUNK;
    int lo = b * per, hi = min(E, lo + per);
    for (int e = lo + t; e < hi; e += 256) {
        int d = dst[e];
        int bk = d >> BSHIFT;
        int pos = atomicAdd(&cur[bk], 1);   // LDS atomic
        colA[pos] = (src[e] << BSHIFT) | (d & (BROWS - 1));
    }
}

// ------------------------------- per-bucket counting sort (in place via LDS)
__global__ __launch_bounds__(256) void build_k(int* __restrict__ colA,
                                               const int* __restrict__ H,
                                               float* __restrict__ dinv,
                                               int* __restrict__ rowp,
                                               int N, int E, int nb) {
    __shared__ int recs[BCAP];
    __shared__ int cnt[BROWS], pfx[BROWS], cur[BROWS];
    int b = blockIdx.x, t = threadIdx.x;
    int base = H[(size_t)b * NCHUNK];
    int next = (b + 1 < nb) ? H[(size_t)(b + 1) * NCHUNK] : E;
    int size = next - base;
    if (size > BCAP) size = BCAP;   // safety clamp (never hit for this graph)
    int row0 = b << BSHIFT;

    if (t < BROWS) { cnt[t] = 0; cur[t] = 0; }
    __syncthreads();

    for (int i = t; i < size; i += 256) {
        int r = colA[base + i];
        recs[i] = r;
        atomicAdd(&cnt[r & (BROWS - 1)], 1);
    }
    __syncthreads();

    if (t < BROWS) pfx[t] = cnt[t];
    __syncthreads();
    for (int off = 1; off < BROWS; off <<= 1) {
        int u = 0;
        if (t < BROWS && t >= off) u = pfx[t - off];
        __syncthreads();
        if (t < BROWS) pfx[t] += u;
        __syncthreads();
    }
    if (t < BROWS) {
        int row = row0 + t;
        if (row < N) {
            int ex = pfx[t] - cnt[t];
            rowp[row] = base + ex;
            dinv[row] = rsqrtf((float)cnt[t] + 1.0f);
            if (row == N - 1) rowp[N] = base + pfx[t];
        }
    }
    __syncthreads();

    for (int i = t; i < size; i += 256) {
        int r = recs[i];
        int l = r & (BROWS - 1);
        int pos = base + (pfx[l] - cnt[l]) + atomicAdd(&cur[l], 1);
        colA[pos] = r >> BSHIFT;
    }
}

// ---------------------- one-time W preconversion: f32 [k][col] -> bf16 [col][k]
// Block 0 additionally zero-inits the stat replicas (replaces hipMemsetAsync,
// which cost ~42us as a graph dispatch). stats2_k re-zeros after each layer.
__global__ __launch_bounds__(256) void wconv_k(const float* __restrict__ W1,
                                               const float* __restrict__ W2,
                                               const float* __restrict__ W3,
                                               ushort_t* __restrict__ Wb,
                                               float* __restrict__ gstat) {
    int t = blockIdx.x * 256 + threadIdx.x;
    if (blockIdx.x == 0) {
        for (int i = threadIdx.x; i < NREP * 128; i += 256) gstat[i] = 0.0f;
    }
    if (t >= 3 * 4096) return;
    int l = t >> 12, i = t & 4095;
    int col = i >> 6, k = i & 63;
    const float* W = (l == 0) ? W1 : ((l == 1) ? W2 : W3);
    Wb[(size_t)l * 4096 + col * 64 + k] = f2bf(W[k * 64 + col]);
}

// ------------------------------------------------- GEMM via MFMA (bf16 in/out)
// R11-proven LDS-staged structure. Block = 64 rows, 4 waves; wave = 16 rows.
// W^T preconverted bf16 (wconv_k) -> straight uint4 copy into LDS.
// MODE==0: fp32 input, no BN. MODE==1: bf16 input + folded BN + ReLU in fp32
// while staging z into LDS. Output y = dinv[row]*(f(z)@W), bf16 row-major.
template <int MODE>
__global__ __launch_bounds__(256) void gemm_k(const float* __restrict__ Zf,
                                              const uint2* __restrict__ Zb,
                                              const ushort_t* __restrict__ Wb,
                                              const float* __restrict__ dinv,
                                              const float* __restrict__ cA,
                                              const float* __restrict__ cC,
                                              ushort_t* __restrict__ XW, int N) {
    __shared__ ushort_t WbT[64 * ZP];
    __shared__ ushort_t Zt[64 * ZP];
    __shared__ ushort_t Ot[4][16 * ZP];
    __shared__ float Al[64], Cl[64], Dl[64];
    int t = threadIdx.x;
    int row0 = blockIdx.x * 64;

    if (t < 64) {
        int r = row0 + t;
        Dl[t] = (r < N) ? dinv[r] : 0.0f;
        if (MODE) { Al[t] = cA[t]; Cl[t] = cC[t]; }
    }
    // stage preconverted W^T: 512 uint4 chunks; thread t copies 2
    {
        const uint4* ws = (const uint4*)Wb;
#pragma unroll
        for (int i = 0; i < 2; ++i) {
            int cid = t * 2 + i;              // 0..511 = col (cid>>3), seg (cid&7)
            int col = cid >> 3, seg = cid & 7;
            *(uint4*)&WbT[col * ZP + seg * 8] = ws[cid];
        }
    }
    __syncthreads();   // Al/Cl ready before staging uses them

    // stage z: row = t>>2, colgroup = t&3 (16 cols each)
    {
        int r = t >> 2, cg = t & 3;
        int grow = row0 + r;
        bool gv = grow < N;
#pragma unroll
        for (int q = 0; q < 4; ++q) {
            float4 v;
            if (MODE) {
                uint2 p2 = {0, 0};
                if (gv) p2 = Zb[(size_t)grow * 16 + cg * 4 + q];
                v.x = bf2f_lo(p2.x); v.y = bf2f_hi(p2.x);
                v.z = bf2f_lo(p2.y); v.w = bf2f_hi(p2.y);
                int k = cg * 16 + q * 4;
                v.x = fmaxf(Al[k + 0] * v.x + Cl[k + 0], 0.0f);
                v.y = fmaxf(Al[k + 1] * v.y + Cl[k + 1], 0.0f);
                v.z = fmaxf(Al[k + 2] * v.z + Cl[k + 2], 0.0f);
                v.w = fmaxf(Al[k + 3] * v.w + Cl[k + 3], 0.0f);
            } else {
                if (gv) v = *(const float4*)(Zf + (size_t)grow * 64 + cg * 16 + q * 4);
                else { v.x = v.y = v.z = v.w = 0.0f; }
            }
            uint2 p;
            p.x = (uint_t)f2bf(v.x) | ((uint_t)f2bf(v.y) << 16);
            p.y = (uint_t)f2bf(v.z) | ((uint_t)f2bf(v.w) << 16);
            *(uint2*)&Zt[r * ZP + cg * 16 + q * 4] = p;
        }
    }
    __syncthreads();

    int wv = t >> 6, lane = t & 63;
    int mrow = lane & 15;    // A row / B col / D col
    int kgrp = lane >> 4;    // k-slice 0..3 (8 k each)

    f32x4 acc0 = {0, 0, 0, 0}, acc1 = {0, 0, 0, 0};
    f32x4 acc2 = {0, 0, 0, 0}, acc3 = {0, 0, 0, 0};
#pragma unroll
    for (int ks = 0; ks < 2; ++ks) {
        bf16x8 a = *(bf16x8*)&Zt[(wv * 16 + mrow) * ZP + ks * 32 + kgrp * 8];
        bf16x8 b0 = *(bf16x8*)&WbT[(0 + mrow) * ZP + ks * 32 + kgrp * 8];
        bf16x8 b1 = *(bf16x8*)&WbT[(16 + mrow) * ZP + ks * 32 + kgrp * 8];
        bf16x8 b2 = *(bf16x8*)&WbT[(32 + mrow) * ZP + ks * 32 + kgrp * 8];
        bf16x8 b3 = *(bf16x8*)&WbT[(48 + mrow) * ZP + ks * 32 + kgrp * 8];
        acc0 = __builtin_amdgcn_mfma_f32_16x16x32_bf16(a, b0, acc0, 0, 0, 0);
        acc1 = __builtin_amdgcn_mfma_f32_16x16x32_bf16(a, b1, acc1, 0, 0, 0);
        acc2 = __builtin_amdgcn_mfma_f32_16x16x32_bf16(a, b2, acc2, 0, 0, 0);
        acc3 = __builtin_amdgcn_mfma_f32_16x16x32_bf16(a, b3, acc3, 0, 0, 0);
    }

    // epilogue: scale by dinv, bf16, stage per-wave tile, coalesced store
#pragma unroll
    for (int r = 0; r < 4; ++r) {
        int orow = kgrp * 4 + r;
        float dn = Dl[wv * 16 + orow];
        Ot[wv][orow * ZP + 0 + mrow]  = f2bf(acc0[r] * dn);
        Ot[wv][orow * ZP + 16 + mrow] = f2bf(acc1[r] * dn);
        Ot[wv][orow * ZP + 32 + mrow] = f2bf(acc2[r] * dn);
        Ot[wv][orow * ZP + 48 + mrow] = f2bf(acc3[r] * dn);
    }
#pragma unroll
    for (int i = 0; i < 2; ++i) {
        int cid = lane * 2 + i;           // 0..127 = 16 rows x 8 chunks (16B)
        int orow = cid >> 3, seg = cid & 7;
        int grow = row0 + wv * 16 + orow;
        if (grow < N)
            *(uint4*)(XW + (size_t)grow * 64 + seg * 8) =
                *(uint4*)&Ot[wv][orow * ZP + seg * 8];
    }
}

// ------------------------------------------------- aggregation + BN partials
// R9/R13 pair structure (measured floor of 5 structural variants): TWO rows
// per wave: rs = lane>>5, g = (lane>>4)&1 (edge group), c = lane&15 (uint2
// col quad). 16-slot chunks; 8 gather instrs x 4 edges = 32 edges in flight
// per wave. y carries dinv[src]; z stored bf16. Stats via replicated global
// atomics (64 blocks/replica -> no hot line).
__global__ __launch_bounds__(256) void agg_k(const ushort_t* __restrict__ y,
                                             const int* __restrict__ row_ptr,
                                             const int* __restrict__ colA,
                                             const float* __restrict__ dinv,
                                             uint2* __restrict__ OUTB,
                                             float* __restrict__ gstat, int N) {
    __shared__ float ssum[64], ssq[64];
    int t = threadIdx.x, lane = t & 63, wv = t >> 6;
    int rs = lane >> 5;          // row within pair
    int g = (lane >> 4) & 1;     // edge group
    int c = lane & 15;           // column quad (cols 4c..4c+3)
    if (t < 64) ssum[t] = 0.0f;
    else if (t < 128) ssq[t - 64] = 0.0f;
    __syncthreads();

    const uint2* y2 = (const uint2*)y;
    float ps0 = 0, ps1 = 0, ps2 = 0, ps3 = 0;
    float pq0 = 0, pq1 = 0, pq2 = 0, pq3 = 0;

    int npair = (N + 1) >> 1;
    for (int p = blockIdx.x * 4 + wv; p < npair; p += NB_AGG * 4) {
        int row = p * 2 + rs;
        bool rv = row < N;
        int rc = rv ? row : N - 1;
        int start = row_ptr[rc];
        int end = row_ptr[rc + 1];
        int len = rv ? (end - start) : 0;
        int ml = max(len, __shfl_xor(len, 32));   // max over the pair

        float a0 = 0, a1 = 0, a2 = 0, a3 = 0;
        for (int off = 0; off < ml; off += 16) {
            int sA[8];
            uint_t mA[8];
#pragma unroll
            for (int u = 0; u < 8; ++u) {
                int slot = off + u * 2 + g;
                bool val = slot < len;
                int ec = val ? (start + slot) : 0;
                sA[u] = colA[ec];
                mA[u] = val ? 0xffffffffu : 0u;
            }
#pragma unroll
            for (int u = 0; u < 8; ++u) {
                uint2 v = y2[(size_t)sA[u] * 16 + c];
                v.x &= mA[u]; v.y &= mA[u];
                a0 += bf2f_lo(v.x);
                a1 += bf2f_hi(v.x);
                a2 += bf2f_lo(v.y);
                a3 += bf2f_hi(v.y);
            }
        }

        // reduce across the 2 edge groups (lane bit 4)
        a0 += __shfl_xor(a0, 16);
        a1 += __shfl_xor(a1, 16);
        a2 += __shfl_xor(a2, 16);
        a3 += __shfl_xor(a3, 16);

        if (g == 0 && rv) {
            float dn = dinv[row];
            uint2 sv = y2[(size_t)row * 16 + c];   // self term (y carries dinv)
            float v0 = dn * (a0 + bf2f_lo(sv.x));
            float v1 = dn * (a1 + bf2f_hi(sv.x));
            float v2 = dn * (a2 + bf2f_lo(sv.y));
            float v3 = dn * (a3 + bf2f_hi(sv.y));
            uint2 pk;
            pk.x = (uint_t)f2bf(v0) | ((uint_t)f2bf(v1) << 16);
            pk.y = (uint_t)f2bf(v2) | ((uint_t)f2bf(v3) << 16);
            OUTB[(size_t)row * 16 + c] = pk;
            ps0 += v0; ps1 += v1; ps2 += v2; ps3 += v3;
            pq0 += v0 * v0; pq1 += v1 * v1; pq2 += v2 * v2; pq3 += v3 * v3;
        }
    }

    if (g == 0) {
        atomicAdd(&ssum[c * 4 + 0], ps0); atomicAdd(&ssq[c * 4 + 0], pq0);
        atomicAdd(&ssum[c * 4 + 1], ps1); atomicAdd(&ssq[c * 4 + 1], pq1);
        atomicAdd(&ssum[c * 4 + 2], ps2); atomicAdd(&ssq[c * 4 + 2], pq2);
        atomicAdd(&ssum[c * 4 + 3], ps3); atomicAdd(&ssq[c * 4 + 3], pq3);
    }
    __syncthreads();
    // replicated global stats: 64 blocks per replica, 8 lines each -> no hot line
    float* gr = gstat + (size_t)(blockIdx.x & (NREP - 1)) * 128;
    if (t < 64) atomicAdd(&gr[t], ssum[t]);
    else if (t < 128) atomicAdd(&gr[t], ssq[t - 64]);
}

// ------------------------- BN coefficients from replicated sums (1 block)
// Reads gstat, computes cA/cC, then re-zeros gstat for the next layer.
__global__ void stats2_k(float* __restrict__ gstat,
                         const float* __restrict__ g,
                         const float* __restrict__ be,
                         float* __restrict__ cA,
                         float* __restrict__ cC, int N) {
    int t = threadIdx.x;
    if (t < 64) {
        float s = 0.0f, q = 0.0f;
        for (int r = 0; r < NREP; ++r) {
            s += gstat[r * 128 + t];
            q += gstat[r * 128 + 64 + t];
        }
        float mu = s / (float)N;
        float var = fmaxf(q / (float)N - mu * mu, 0.0f);
        float a = g[t] * rsqrtf(var + 1e-5f);
        cA[t] = a;
        cC[t] = be[t] - mu * a;
    }
    __syncthreads();
    for (int i = t; i < NREP * 128; i += 256) gstat[i] = 0.0f;
}

// --------------------------------- final BN apply: bf16 z -> fp32 output
__global__ __launch_bounds__(256) void apply_k(const uint2* __restrict__ Zb,
                                               float* __restrict__ O,
                                               const float* __restrict__ cA,
                                               const float* __restrict__ cC,
                                               int N) {
    int total = N * 16;  // uint2 count
    for (int i = blockIdx.x * 256 + threadIdx.x; i < total; i += gridDim.x * 256) {
        uint2 p = Zb[i];
        int c = (i & 15) * 4;
        float4 v;
        v.x = cA[c + 0] * bf2f_lo(p.x) + cC[c + 0];
        v.y = cA[c + 1] * bf2f_hi(p.x) + cC[c + 1];
        v.z = cA[c + 2] * bf2f_lo(p.y) + cC[c + 2];
        v.w = cA[c + 3] * bf2f_hi(p.y) + cC[c + 3];
        ((float4*)O)[i] = v;
    }
}

// ---------------------------------------------------------------------------
extern "C" void kernel_launch(void* const* d_in, const int* in_sizes, int n_in,
                              void* d_out, int out_size, void* d_ws, size_t ws_size,
                              hipStream_t stream) {
    const float* x   = (const float*)d_in[0];
    const int*   ei  = (const int*)d_in[1];
    const float* W1  = (const float*)d_in[2];
    const float* g1  = (const float*)d_in[4];
    const float* be1 = (const float*)d_in[5];
    const float* W2  = (const float*)d_in[6];
    const float* g2  = (const float*)d_in[8];
    const float* be2 = (const float*)d_in[9];
    const float* W3  = (const float*)d_in[10];
    const float* g3  = (const float*)d_in[12];
    const float* be3 = (const float*)d_in[13];

    int N = in_sizes[0] / 64;
    int E = in_sizes[1] / 2;
    const int* srcA = ei;
    const int* dstA = ei + E;
    int nb = (N + BROWS - 1) >> BSHIFT;          // <=1024 for N<=131072
    int total = nb * NCHUNK;                     // multi-split matrix size
    int nseg = (total + 1023) / 1024;            // <=256

    char* w = (char*)d_ws;
    auto alloc = [&](size_t bytes) -> char* {
        char* p = w;
        w += (bytes + 255) & ~(size_t)255;
        return p;
    };
    ushort_t* xw    = (ushort_t*)alloc((size_t)N * 64 * 2);   // staged y (bf16)
    uint2*    zb    = (uint2*)alloc((size_t)N * 64 * 2);      // intermediate z (bf16)
    ushort_t* Wb    = (ushort_t*)alloc((size_t)3 * 4096 * 2); // preconverted W^T
    int*      rowp  = (int*)alloc(((size_t)N + 1) * 4);
    float*    dinv  = (float*)alloc((size_t)N * 4);
    int*      colA  = (int*)alloc((size_t)E * 4);
    int*      H     = (int*)alloc((size_t)total * 4);
    int*      segsum= (int*)alloc((size_t)nseg * 4);
    float*    gstat = (float*)alloc((size_t)NREP * 128 * 4);  // stat replicas
    float*    cA1 = (float*)alloc(256); float* cC1 = (float*)alloc(256);
    float*    cA2 = (float*)alloc(256); float* cC2 = (float*)alloc(256);
    float*    cA3 = (float*)alloc(256); float* cC3 = (float*)alloc(256);
    (void)ws_size; (void)n_in; (void)out_size;

    float* out = (float*)d_out;

    // ---- CSR build via atomic-free multi-split (once; shared by 3 layers) ----
    hist2_k<<<NCHUNK, 256, 0, stream>>>(dstA, H, E, nb);
    scanA_k<<<nseg, 256, 0, stream>>>(H, segsum, total);
    scanB_k<<<1, 256, 0, stream>>>(segsum, nseg);
    scanC2_k<<<nseg, 256, 0, stream>>>(H, segsum, total);
    scat2_k<<<NCHUNK, 256, 0, stream>>>(srcA, dstA, H, colA, E, nb);
    build_k<<<nb, 256, 0, stream>>>(colA, H, dinv, rowp, N, E, nb);
    wconv_k<<<48, 256, 0, stream>>>(W1, W2, W3, Wb, gstat);

    int gemmGrid = (N + 63) / 64;

    // ---- layer 1 ----
    gemm_k<0><<<gemmGrid, 256, 0, stream>>>(x, nullptr, Wb, dinv, nullptr, nullptr, xw, N);
    agg_k<<<NB_AGG, 256, 0, stream>>>(xw, rowp, colA, dinv, zb, gstat, N);
    stats2_k<<<1, 256, 0, stream>>>(gstat, g1, be1, cA1, cC1, N);

    // ---- layer 2 ----
    gemm_k<1><<<gemmGrid, 256, 0, stream>>>(nullptr, zb, Wb + 4096, dinv, cA1, cC1, xw, N);
    agg_k<<<NB_AGG, 256, 0, stream>>>(xw, rowp, colA, dinv, zb, gstat, N);
    stats2_k<<<1, 256, 0, stream>>>(gstat, g2, be2, cA2, cC2, N);

    // ---- layer 3 ----
    gemm_k<1><<<gemmGrid, 256, 0, stream>>>(nullptr, zb, Wb + 8192, dinv, cA2, cC2, xw, N);
    agg_k<<<NB_AGG, 256, 0, stream>>>(xw, rowp, colA, dinv, zb, gstat, N);
    stats2_k<<<1, 256, 0, stream>>>(gstat, g3, be3, cA3, cC3, N);

    // ---- final BN (no relu): bf16 z -> fp32 d_out ----
    apply_k<<<2048, 256, 0, stream>>>(zb, out, cA3, cC3, N);
}